// Round 5
// baseline (392.595 us; speedup 1.0000x reference)
//
#include <hip/hip_runtime.h>

// ---------------------------------------------------------------------------
// LabelCrossAttentionDE: out[b,c] = LN(softmax(Q K^T) V) . out_w + out_b
// B=2, S=4096, C=8000, D=768, SCALE=1 (fp16 MFMA path, fp32 accumulate)
// K/V in MFMA fragment order (coalesced 1KB wave-streams).
// Attention: CT=64, 1 block/CU; deep rolling register prefetch for K (8) and
// V (4/stream) that crosses tile boundaries -> loads stay ~2000cy in flight.
// ---------------------------------------------------------------------------

typedef _Float16 half8  __attribute__((ext_vector_type(8)));
typedef _Float16 half4v __attribute__((ext_vector_type(4)));
typedef float    f32x4  __attribute__((ext_vector_type(4)));
typedef float    f32x16 __attribute__((ext_vector_type(16)));

#define L2E 1.44269504088896340736f

__device__ __forceinline__ void gld_lds16(_Float16* lds, const _Float16* g) {
  __builtin_amdgcn_global_load_lds(
      (const __attribute__((address_space(1))) unsigned int*)g,
      (__attribute__((address_space(3))) unsigned int*)lds, 16, 0, 0);
}

// ------------------------------ f32 -> f16 ---------------------------------
__global__ void cvt_kernel(const float* __restrict__ src, _Float16* __restrict__ dst, int n4) {
  int i = blockIdx.x * blockDim.x + threadIdx.x;
  if (i >= n4) return;
  float4 v = reinterpret_cast<const float4*>(src)[i];
  half4v h; h[0] = (_Float16)v.x; h[1] = (_Float16)v.y; h[2] = (_Float16)v.z; h[3] = (_Float16)v.w;
  reinterpret_cast<half4v*>(dst)[i] = h;
}

// ---------------- GEMM: C = A[M,768] @ Bt[N,768]^T (+bias[row]) -------------
// MODE 1: K fragment layout.  (row=s, col=d) ->
//         ((s>>5)*48 + (d>>4))*512 + (s&31)*16 + (d&15)
// MODE 2: V fragment layout.  (row=e, col=s_global) ->
//         (((s>>12)*24 + (e>>5))*256 + ((s&4095)>>4))*512 + (e&31)*16 + (s&15)
template <int MODE>
__global__ __launch_bounds__(256, 2) void gemm_nt_f16(
    const _Float16* __restrict__ A, const _Float16* __restrict__ Bt,
    _Float16* __restrict__ C, const float* __restrict__ bias, int M, int N)
{
  __shared__ __align__(16) _Float16 As[2][128 * 64];
  __shared__ __align__(16) _Float16 Bs[2][128 * 64];
  const int tid = threadIdx.x;
  const int lane = tid & 63, wid = tid >> 6;
  const int ntn = N >> 7;
  const int mtile = blockIdx.x / ntn, ntile = blockIdx.x - mtile * ntn;
  const int m0 = mtile << 7, n0 = ntile << 7;
  const int wm = wid >> 1, wn = wid & 1;

  f32x4 acc[4][4] = {};

  auto stage = [&](int buf, int kt) {
#pragma unroll
    for (int j = 0; j < 4; ++j) {
      int idx = (j << 8) + tid;
      int row = idx >> 3, slot = idx & 7;
      int gc = (kt << 6) + ((slot ^ (row & 7)) << 3);
      _Float16* ldsbase_a = &As[buf][(size_t)(((j << 8) + (wid << 6)) << 3)];
      _Float16* ldsbase_b = &Bs[buf][(size_t)(((j << 8) + (wid << 6)) << 3)];
      gld_lds16(ldsbase_a, &A[(size_t)(m0 + row) * 768 + gc]);
      gld_lds16(ldsbase_b, &Bt[(size_t)(n0 + row) * 768 + gc]);
    }
  };

  stage(0, 0);
  __syncthreads();

  for (int kt = 0; kt < 12; ++kt) {
    int cur = kt & 1;
    if (kt < 11) stage(cur ^ 1, kt + 1);
#pragma unroll
    for (int ks = 0; ks < 2; ++ks) {
      half8 a[4], b[4];
      int dloc = (ks << 5) + ((lane >> 4) << 3);
#pragma unroll
      for (int mi = 0; mi < 4; ++mi) {
        int row = (wm << 6) + (mi << 4) + (lane & 15);
        a[mi] = *reinterpret_cast<const half8*>(&As[cur][row * 64 + (dloc ^ ((row & 7) << 3))]);
      }
#pragma unroll
      for (int ni = 0; ni < 4; ++ni) {
        int row = (wn << 6) + (ni << 4) + (lane & 15);
        b[ni] = *reinterpret_cast<const half8*>(&Bs[cur][row * 64 + (dloc ^ ((row & 7) << 3))]);
      }
#pragma unroll
      for (int mi = 0; mi < 4; ++mi)
#pragma unroll
        for (int ni = 0; ni < 4; ++ni)
          acc[mi][ni] = __builtin_amdgcn_mfma_f32_16x16x32_f16(a[mi], b[ni], acc[mi][ni], 0, 0, 0);
    }
    __syncthreads();
  }

#pragma unroll
  for (int mi = 0; mi < 4; ++mi)
#pragma unroll
    for (int ni = 0; ni < 4; ++ni) {
      int col = n0 + (wn << 6) + (ni << 4) + (lane & 15);
#pragma unroll
      for (int r = 0; r < 4; ++r) {
        int row = m0 + (wm << 6) + (mi << 4) + ((lane >> 4) << 2) + r;
        float v = acc[mi][ni][r];
        if (bias) v += bias[row];
        size_t a;
        if (MODE == 1) {
          a = ((size_t)(row >> 5) * 48 + (col >> 4)) * 512 + (row & 31) * 16 + (col & 15);
        } else {
          a = (((size_t)(col >> 12) * 24 + (row >> 5)) * 256 + ((col & 4095) >> 4)) * 512
              + (row & 31) * 16 + (col & 15);
        }
        C[a] = (_Float16)v;
      }
    }
}

// --------------------------- fused attention -------------------------------
// 8 waves, 64 c-rows/block, S tiles of 256; 1 block/CU (250 blocks).
// Swapped QK (A=K,B=Q): lane owns cols c=l31 and c=l31+32. Softmax running
// state (m, r, l) in registers; 2 barriers/tile. Deep rolling prefetch.
#define QS_STRIDE 776
#define PS_STRIDE 264

__global__ __launch_bounds__(512, 2) void attn_kernel(
    const float* __restrict__ Qf, const _Float16* __restrict__ Kf,
    const _Float16* __restrict__ Vf,
    const float* __restrict__ gamma, const float* __restrict__ beta,
    const float* __restrict__ outw, const float* __restrict__ outb,
    float* __restrict__ out)
{
  __shared__ __align__(16) _Float16 Qs[64 * QS_STRIDE];  // 99,328 B
  __shared__ __align__(16) _Float16 Ps[64 * PS_STRIDE];  // 33,792 B
  __shared__ float redmax[8 * 64];
  __shared__ float redsum[8 * 64];
  __shared__ float gws[768];
  __shared__ float epi[64 * 25];
  __shared__ float lrowS[64];
  __shared__ float scal[2];

  const int tid = threadIdx.x;
  const int lane = tid & 63;
  const int wid = tid >> 6;
  const int l31 = lane & 31;
  const int lh = lane >> 5;

  // bijective XCD swizzle for 250 blocks (q=31, r=2)
  int xcd = blockIdx.x & 7, i8 = blockIdx.x >> 3;
  int f = (xcd < 2) ? (xcd * 32 + i8) : (64 + (xcd - 2) * 31 + i8);
  const int bb = f / 125;
  const int ct = f - bb * 125;
  const int c0 = ct << 6;

  const int n0w = wid * 96;
  const int laneoff = l31 * 16 + lh * 8;
  const _Float16* kfb = Kf + ((size_t)(bb * 128 + wid) * 48) * 512 + laneoff;
  const _Float16* vfb = Vf + ((size_t)(bb * 24 + wid * 3) * 256) * 512 + laneoff;

  // ---- deep prologue prefetch: tile 0's K (depth 8) and V (depth 4x3) ----
  uint4 kp[8];
#pragma unroll
  for (int j = 0; j < 8; ++j) kp[j] = *reinterpret_cast<const uint4*>(kfb + j * 512);
  uint4 vp[4][3];
#pragma unroll
  for (int j = 0; j < 4; ++j) {
    vp[j][0] = *reinterpret_cast<const uint4*>(vfb + j * 512);
    vp[j][1] = *reinterpret_cast<const uint4*>(vfb + 131072 + j * 512);
    vp[j][2] = *reinterpret_cast<const uint4*>(vfb + 262144 + j * 512);
  }

  // ---- stage Q: fp32 -> fp16 into LDS (64 rows x 768) ----
#pragma unroll
  for (int i = 0; i < 24; ++i) {
    int idx = tid + (i << 9);
    int row = idx / 192, c4 = idx - row * 192;
    float4 v = reinterpret_cast<const float4*>(Qf)[(size_t)(c0 + row) * 192 + c4];
    half4v h; h[0] = (_Float16)v.x; h[1] = (_Float16)v.y; h[2] = (_Float16)v.z; h[3] = (_Float16)v.w;
    *reinterpret_cast<half4v*>(&Qs[row * QS_STRIDE + (c4 << 2)]) = h;
  }
  for (int i = tid; i < 768; i += 512) gws[i] = gamma[i] * outw[i];
  __syncthreads();
  if (tid < 64) {  // scal[0]=sum(gamma*w), scal[1]=sum(beta*w)
    float g = 0.f, bw = 0.f;
#pragma unroll
    for (int j = 0; j < 12; ++j) { int d = tid + (j << 6); g += gws[d]; bw += beta[d] * outw[d]; }
#pragma unroll
    for (int m = 32; m; m >>= 1) { g += __shfl_xor(g, m); bw += __shfl_xor(bw, m); }
    if (tid == 0) { scal[0] = g; scal[1] = bw; }
  }

  // per-lane replicated softmax state for columns c=l31 (0) and c=l31+32 (1)
  float mrow0 = -1e30f, mrow1 = -1e30f, lrow0 = 0.f, lrow1 = 0.f;

  f32x16 acc00 = {}, acc01 = {}, acc02 = {};  // rows c 0-31  x 96 e-cols
  f32x16 acc10 = {}, acc11 = {}, acc12 = {};  // rows c 32-63 x 96 e-cols
  const _Float16* qrow0 = &Qs[l31 * QS_STRIDE + (lh << 3)];
  const _Float16* qrow1 = qrow0 + 32 * QS_STRIDE;

  for (int st = 0; st < 16; ++st) {
    const _Float16* kbc = kfb + (size_t)st * 196608;   // this tile's K base
    const _Float16* kbn = kbc + 196608;                // next tile's K base
    const _Float16* vb  = vfb + (size_t)st * 8192;     // this tile's V base
    const _Float16* vbn = vb + 8192;                   // next tile's V base

    // ===================== QK^T (rolling depth-8, crosses tile bound) ======
    f32x16 qk0 = {}, qk1 = {};
#pragma unroll
    for (int k = 0; k < 48; ++k) {
      half8 kf = __builtin_bit_cast(half8, kp[k & 7]);
      if (k < 40)        kp[k & 7] = *reinterpret_cast<const uint4*>(kbc + (k + 8) * 512);
      else if (st < 15)  kp[k & 7] = *reinterpret_cast<const uint4*>(kbn + (k - 40) * 512);
      half8 qf0 = *reinterpret_cast<const half8*>(qrow0 + (k << 4));
      half8 qf1 = *reinterpret_cast<const half8*>(qrow1 + (k << 4));
      qk0 = __builtin_amdgcn_mfma_f32_32x32x16_f16(kf, qf0, qk0, 0, 0, 0);
      qk1 = __builtin_amdgcn_mfma_f32_32x32x16_f16(kf, qf1, qk1, 0, 0, 0);
    }

    // ===================== softmax (state in registers, 2 barriers) =========
    float mx0 = qk0[0], mx1 = qk1[0];
#pragma unroll
    for (int r = 1; r < 16; ++r) { mx0 = fmaxf(mx0, qk0[r]); mx1 = fmaxf(mx1, qk1[r]); }
    mx0 = fmaxf(mx0, __shfl_xor(mx0, 32));
    mx1 = fmaxf(mx1, __shfl_xor(mx1, 32));
    if (lh == 0) {
      redmax[(wid << 6) + l31] = mx0;
      redmax[(wid << 6) + 32 + l31] = mx1;
    }
    __syncthreads();                                   // bar A
    float pm0 = redmax[l31], pm1 = redmax[32 + l31];
#pragma unroll
    for (int w = 1; w < 8; ++w) {
      pm0 = fmaxf(pm0, redmax[(w << 6) + l31]);
      pm1 = fmaxf(pm1, redmax[(w << 6) + 32 + l31]);
    }
    float mn0 = fmaxf(mrow0, pm0), mn1 = fmaxf(mrow1, pm1);
    float rr0 = exp2f((mrow0 - mn0) * L2E), rr1 = exp2f((mrow1 - mn1) * L2E);
    mrow0 = mn0; mrow1 = mn1;

    float sum0 = 0.f, sum1 = 0.f;
    const int sb = (wid << 5) + (lh << 2);
#pragma unroll
    for (int q2 = 0; q2 < 4; ++q2) {
      float p0 = exp2f((qk0[4 * q2 + 0] - mn0) * L2E);
      float p1 = exp2f((qk0[4 * q2 + 1] - mn0) * L2E);
      float p2 = exp2f((qk0[4 * q2 + 2] - mn0) * L2E);
      float p3 = exp2f((qk0[4 * q2 + 3] - mn0) * L2E);
      sum0 += (p0 + p1) + (p2 + p3);
      half4v h; h[0] = (_Float16)p0; h[1] = (_Float16)p1; h[2] = (_Float16)p2; h[3] = (_Float16)p3;
      *reinterpret_cast<half4v*>(&Ps[l31 * PS_STRIDE + sb + (q2 << 3)]) = h;
      float u0 = exp2f((qk1[4 * q2 + 0] - mn1) * L2E);
      float u1 = exp2f((qk1[4 * q2 + 1] - mn1) * L2E);
      float u2 = exp2f((qk1[4 * q2 + 2] - mn1) * L2E);
      float u3 = exp2f((qk1[4 * q2 + 3] - mn1) * L2E);
      sum1 += (u0 + u1) + (u2 + u3);
      half4v h2; h2[0] = (_Float16)u0; h2[1] = (_Float16)u1; h2[2] = (_Float16)u2; h2[3] = (_Float16)u3;
      *reinterpret_cast<half4v*>(&Ps[(32 + l31) * PS_STRIDE + sb + (q2 << 3)]) = h2;
    }
    sum0 += __shfl_xor(sum0, 32);
    sum1 += __shfl_xor(sum1, 32);
    if (lh == 0) {
      redsum[(wid << 6) + l31] = sum0;
      redsum[(wid << 6) + 32 + l31] = sum1;
    }
    // conditional rescale (skipped when running max didn't grow: rr==1)
    if (__any(rr0 < 1.0f) || __any(rr1 < 1.0f)) {
#pragma unroll
      for (int r = 0; r < 16; ++r) {
        int crow = (r & 3) + ((r >> 2) << 3) + (lh << 2);
        float rs0 = __shfl(rr0, crow);
        float rs1 = __shfl(rr1, crow);
        acc00[r] *= rs0; acc01[r] *= rs0; acc02[r] *= rs0;
        acc10[r] *= rs1; acc11[r] *= rs1; acc12[r] *= rs1;
      }
    }
    __syncthreads();                                   // bar B
    {
      float s0 = redsum[l31], s1 = redsum[32 + l31];
#pragma unroll
      for (int w = 1; w < 8; ++w) {
        s0 += redsum[(w << 6) + l31];
        s1 += redsum[(w << 6) + 32 + l31];
      }
      lrow0 = lrow0 * rr0 + s0;
      lrow1 = lrow1 * rr1 + s1;
    }
    // ===================== PV (rolling depth-4/stream, crosses tile) =======
#pragma unroll
    for (int ks = 0; ks < 16; ++ks) {
      half8 b0 = __builtin_bit_cast(half8, vp[ks & 3][0]);
      half8 b1 = __builtin_bit_cast(half8, vp[ks & 3][1]);
      half8 b2 = __builtin_bit_cast(half8, vp[ks & 3][2]);
      if (ks < 12) {
        vp[ks & 3][0] = *reinterpret_cast<const uint4*>(vb + (ks + 4) * 512);
        vp[ks & 3][1] = *reinterpret_cast<const uint4*>(vb + 131072 + (ks + 4) * 512);
        vp[ks & 3][2] = *reinterpret_cast<const uint4*>(vb + 262144 + (ks + 4) * 512);
      } else if (st < 15) {
        vp[ks & 3][0] = *reinterpret_cast<const uint4*>(vbn + (ks - 12) * 512);
        vp[ks & 3][1] = *reinterpret_cast<const uint4*>(vbn + 131072 + (ks - 12) * 512);
        vp[ks & 3][2] = *reinterpret_cast<const uint4*>(vbn + 262144 + (ks - 12) * 512);
      }
      half8 pa0 = *reinterpret_cast<const half8*>(&Ps[l31 * PS_STRIDE + (ks << 4) + (lh << 3)]);
      half8 pa1 = *reinterpret_cast<const half8*>(&Ps[(32 + l31) * PS_STRIDE + (ks << 4) + (lh << 3)]);
      acc00 = __builtin_amdgcn_mfma_f32_32x32x16_f16(pa0, b0, acc00, 0, 0, 0);
      acc01 = __builtin_amdgcn_mfma_f32_32x32x16_f16(pa0, b1, acc01, 0, 0, 0);
      acc02 = __builtin_amdgcn_mfma_f32_32x32x16_f16(pa0, b2, acc02, 0, 0, 0);
      acc10 = __builtin_amdgcn_mfma_f32_32x32x16_f16(pa1, b0, acc10, 0, 0, 0);
      acc11 = __builtin_amdgcn_mfma_f32_32x32x16_f16(pa1, b1, acc11, 0, 0, 0);
      acc12 = __builtin_amdgcn_mfma_f32_32x32x16_f16(pa1, b2, acc12, 0, 0, 0);
    }
  }

  // ===================== fused LN + projection epilogue =====================
  if (wid == 0 && lh == 0) { lrowS[l31] = lrow0; lrowS[32 + l31] = lrow1; }
  float gw0 = gws[n0w + l31];
  float gw1 = gws[n0w + 32 + l31];
  float gw2 = gws[n0w + 64 + l31];
#pragma unroll
  for (int r = 0; r < 16; ++r) {
    int c = (r & 3) + ((r >> 2) << 3) + (lh << 2);
    {
      float y0 = acc00[r], y1 = acc01[r], y2 = acc02[r];
      float t1 = y0 + y1 + y2;
      float t2 = y0 * y0 + y1 * y1 + y2 * y2;
      float t3 = y0 * gw0 + y1 * gw1 + y2 * gw2;
#pragma unroll
      for (int m = 1; m <= 16; m <<= 1) {
        t1 += __shfl_xor(t1, m); t2 += __shfl_xor(t2, m); t3 += __shfl_xor(t3, m);
      }
      if (l31 == 0) { float* e = &epi[c * 25 + wid * 3]; e[0] = t1; e[1] = t2; e[2] = t3; }
    }
    {
      float y0 = acc10[r], y1 = acc11[r], y2 = acc12[r];
      float t1 = y0 + y1 + y2;
      float t2 = y0 * y0 + y1 * y1 + y2 * y2;
      float t3 = y0 * gw0 + y1 * gw1 + y2 * gw2;
#pragma unroll
      for (int m = 1; m <= 16; m <<= 1) {
        t1 += __shfl_xor(t1, m); t2 += __shfl_xor(t2, m); t3 += __shfl_xor(t3, m);
      }
      if (l31 == 0) { float* e = &epi[(32 + c) * 25 + wid * 3]; e[0] = t1; e[1] = t2; e[2] = t3; }
    }
  }
  __syncthreads();
  if (tid < 64) {
    float S1 = 0.f, S2 = 0.f, S3 = 0.f;
#pragma unroll
    for (int w = 0; w < 8; ++w) {
      const float* e = &epi[tid * 25 + w * 3];
      S1 += e[0]; S2 += e[1]; S3 += e[2];
    }
    float l = lrowS[tid];
    float invl = 1.0f / l;
    float mu = S1 * invl * (1.0f / 768.0f);
    float ey2 = S2 * invl * invl * (1.0f / 768.0f);
    float var = ey2 - mu * mu;
    float rs = rsqrtf(var + 1e-5f);
    float res = rs * (S3 * invl - mu * scal[0]) + scal[1] + outb[0];
    out[bb * 8000 + c0 + tid] = res;
  }
}

// ---------------------------------------------------------------------------
extern "C" void kernel_launch(void* const* d_in, const int* in_sizes, int n_in,
                              void* d_out, int out_size, void* d_ws, size_t ws_size,
                              hipStream_t stream) {
  (void)in_sizes; (void)n_in; (void)out_size; (void)ws_size;
  const float* x     = (const float*)d_in[0];
  const float* qenc  = (const float*)d_in[1];
  const float* Wk    = (const float*)d_in[2];
  const float* Wv    = (const float*)d_in[3];
  const float* bv    = (const float*)d_in[4];
  const float* gam   = (const float*)d_in[5];
  const float* bet   = (const float*)d_in[6];
  const float* outw  = (const float*)d_in[7];
  const float* outb  = (const float*)d_in[8];
  float* out = (float*)d_out;

  char* ws = (char*)d_ws;
  _Float16* x_h  = (_Float16*)(ws);                  // 8192x768
  _Float16* wk_h = (_Float16*)(ws + 12582912);       // 768x768
  _Float16* wv_h = (_Float16*)(ws + 13762560);       // 768x768
  _Float16* K_f  = (_Float16*)(ws + 14942208);       // frag layout, 12.6 MB
  _Float16* V_f  = (_Float16*)(ws + 27525120);       // frag layout, 12.6 MB

  cvt_kernel<<<6144, 256, 0, stream>>>(x, x_h, 1572864);
  cvt_kernel<<<576, 256, 0, stream>>>(Wk, wk_h, 147456);
  cvt_kernel<<<576, 256, 0, stream>>>(Wv, wv_h, 147456);
  // K[s,e] = x @ Wk^T  -> fragment layout
  gemm_nt_f16<1><<<384, 256, 0, stream>>>(x_h, wk_h, K_f, nullptr, 8192, 768);
  // V^T[e,s] = Wv @ x^T + bv -> fragment layout
  gemm_nt_f16<2><<<384, 256, 0, stream>>>(wv_h, x_h, V_f, bv, 768, 8192);
  attn_kernel<<<250, 512, 0, stream>>>(qenc, K_f, V_f, gam, bet, outw, outb, out);
}